// Round 1
// baseline (309.047 us; speedup 1.0000x reference)
//
#include <hip/hip_runtime.h>
#include <math.h>

#define T_NTIME  2048
#define T_NBATCH 128
#define T_INSIZE 512
#define T_SIZE   16
#define T_NROWS  (T_NTIME * T_NBATCH)

__device__ __forceinline__ float sp_f(float v) {
  // softplus, stable: max(v,0) + log1p(exp(-|v|))
  return fmaxf(v, 0.0f) + log1pf(__expf(-fabsf(v)));
}
__device__ __forceinline__ float tanh5_f(float v) {
  float a = fabsf(v);
  float e = __expf(-2.0f * a);
  float t = (1.0f - e) / (1.0f + e);
  return copysignf(5.0f * t, v);
}
__device__ __forceinline__ float lae_f(float a, float c) {
  // logaddexp, stable
  float m = fmaxf(a, c);
  return m + log1pf(__expf(-fabsf(a - c)));
}

__device__ __forceinline__ void emit_row(float* op, const float (&acc)[T_SIZE],
                                         const float (&bv)[T_SIZE]) {
  float y[T_SIZE];
#pragma unroll
  for (int s = 0; s < T_SIZE; ++s) y[s] = acc[s] + bv[s];
  float4 v;
  v.x = 1.0f + sp_f(y[0]);  v.y = 1.0f + sp_f(y[1]);
  v.z = 1.0f + sp_f(y[2]);  v.w = 1.0f + sp_f(y[3]);
  *(float4*)(op + 0) = v;
  v.x = 0.1f + sp_f(y[4]);  v.y = 0.1f + sp_f(y[5]);
  v.z = 0.1f + sp_f(y[6]);  v.w = 0.1f + sp_f(y[7]);
  *(float4*)(op + 4) = v;
  v.x = tanh5_f(y[8]);  v.y = tanh5_f(y[9]);
  v.z = tanh5_f(y[10]); v.w = tanh5_f(y[11]);
  *(float4*)(op + 8) = v;
  v.x = tanh5_f(y[12]); v.y = tanh5_f(y[13]);
  v.z = tanh5_f(y[14]); v.w = tanh5_f(y[15]);
  *(float4*)(op + 12) = v;
}

// ---------- K1: y = x @ W^T + b, activations; trans written pre-logZ ----------
__global__ __launch_bounds__(256, 2)
void k_gemm_act(const float* __restrict__ x, const float* __restrict__ W,
                const float* __restrict__ bias, float* __restrict__ out) {
  __shared__ float wl[T_SIZE * T_INSIZE];  // 32 KB
  const int tid = threadIdx.x;
  {
    const float4* src = (const float4*)W;
    float4* dst = (float4*)wl;
#pragma unroll
    for (int k = 0; k < (T_SIZE * T_INSIZE / 4) / 256; ++k)
      dst[tid + k * 256] = src[tid + k * 256];
  }
  float bv[T_SIZE];
#pragma unroll
  for (int s = 0; s < T_SIZE; ++s) bv[s] = bias[s];
  __syncthreads();

  const long row0 = (long)blockIdx.x * 512 + tid;  // rows row0 and row0+256
  const float* __restrict__ xr0 = x + row0 * T_INSIZE;
  const float* __restrict__ xr1 = xr0 + 256L * T_INSIZE;

  float acc0[T_SIZE], acc1[T_SIZE];
#pragma unroll
  for (int s = 0; s < T_SIZE; ++s) { acc0[s] = 0.0f; acc1[s] = 0.0f; }

  for (int c = 0; c < T_INSIZE / 4; ++c) {
    const float4 xa = *(const float4*)(xr0 + c * 4);
    const float4 xb = *(const float4*)(xr1 + c * 4);
#pragma unroll
    for (int s = 0; s < T_SIZE; ++s) {
      const float4 w4 = *(const float4*)(wl + s * T_INSIZE + c * 4);  // uniform addr -> broadcast
      acc0[s] = fmaf(xa.x, w4.x, acc0[s]);
      acc0[s] = fmaf(xa.y, w4.y, acc0[s]);
      acc0[s] = fmaf(xa.z, w4.z, acc0[s]);
      acc0[s] = fmaf(xa.w, w4.w, acc0[s]);
      acc1[s] = fmaf(xb.x, w4.x, acc1[s]);
      acc1[s] = fmaf(xb.y, w4.y, acc1[s]);
      acc1[s] = fmaf(xb.z, w4.z, acc1[s]);
      acc1[s] = fmaf(xb.w, w4.w, acc1[s]);
    }
  }
  emit_row(out + row0 * T_SIZE, acc0, bv);
  emit_row(out + (row0 + 256L) * T_SIZE, acc1, bv);
}

// ---------- K2a: per-(b, chunk, basis-col) run the recurrence on basis cols ----------
// Augmented 5-state linear (in exp-space) recurrence; col k of chunk transfer matrix.
// fwd'[i]_new = logaddexp(fwd'[i]+stay_i, move_i + lse({fwd'[j]: j!=i} u {t4}))
// t4 (row 4) is constant through a chunk.
__global__ void k_scan_chunks(const float* __restrict__ out, float* __restrict__ mats,
                              int nchunks) {
  const int gtid = blockIdx.x * blockDim.x + threadIdx.x;
  const int colslot = gtid & 7;
  const int b = (gtid >> 3) & (T_NBATCH - 1);
  const int chunk = gtid >> 10;
  if (chunk >= nchunks) return;
  if (colslot >= 5) return;

  const int steps = T_NTIME / nchunks;
  const int t0 = chunk * steps;
  const float NEG = -1e30f;
  float f0 = (colslot == 0) ? 0.0f : NEG;
  float f1 = (colslot == 1) ? 0.0f : NEG;
  float f2 = (colslot == 2) ? 0.0f : NEG;
  float f3 = (colslot == 3) ? 0.0f : NEG;
  const float t4 = (colslot == 4) ? 0.0f : NEG;

  const float* p = out + ((long)t0 * T_NBATCH + b) * T_SIZE + 8;
  for (int s = 0; s < steps; ++s, p += T_NBATCH * T_SIZE) {
    const float4 mv = *(const float4*)(p);      // move: trans ch 0..3
    const float4 st = *(const float4*)(p + 4);  // stay: trans ch 4..7

    float m, ss0, ss1, ss2, ss3;
    m = fmaxf(fmaxf(f1, f2), fmaxf(f3, t4));
    ss0 = m + __logf(__expf(f1 - m) + __expf(f2 - m) + __expf(f3 - m) + __expf(t4 - m));
    m = fmaxf(fmaxf(f0, f2), fmaxf(f3, t4));
    ss1 = m + __logf(__expf(f0 - m) + __expf(f2 - m) + __expf(f3 - m) + __expf(t4 - m));
    m = fmaxf(fmaxf(f0, f1), fmaxf(f3, t4));
    ss2 = m + __logf(__expf(f0 - m) + __expf(f1 - m) + __expf(f3 - m) + __expf(t4 - m));
    m = fmaxf(fmaxf(f0, f1), fmaxf(f2, t4));
    ss3 = m + __logf(__expf(f0 - m) + __expf(f1 - m) + __expf(f2 - m) + __expf(t4 - m));

    const float n0 = lae_f(f0 + st.x, ss0 + mv.x);
    const float n1 = lae_f(f1 + st.y, ss1 + mv.y);
    const float n2 = lae_f(f2 + st.z, ss2 + mv.z);
    const float n3 = lae_f(f3 + st.w, ss3 + mv.w);
    f0 = n0; f1 = n1; f2 = n2; f3 = n3;
  }
  float* d = mats + (((long)chunk * T_NBATCH + b) * 5 + colslot) * 4;
  d[0] = f0; d[1] = f1; d[2] = f2; d[3] = f3;
}

// ---------- K2b: serial combine of chunk matrices per batch; logZ/T out ----------
__global__ void k_combine(const float* __restrict__ mats, float* __restrict__ logz,
                          int nchunks) {
  const int tid = threadIdx.x;       // 0..511
  const int i = tid & 3;             // state row
  const int b = tid >> 2;            // batch
  if (b >= T_NBATCH) return;
  float v = 0.0f;                    // v[i]; implicit v[4] = 0 constant
  for (int c = 0; c < nchunks; ++c) {
    const float* T = mats + ((long)c * T_NBATCH + b) * 20;  // T[col*4 + row] = T_c[row][col]
    const float vx1 = __shfl_xor(v, 1);
    const float vx2 = __shfl_xor(v, 2);
    const float vx3 = __shfl_xor(v, 3);
    const float a0 = T[i * 4 + i] + v;             // j == i
    const float a1 = T[(i ^ 1) * 4 + i] + vx1;     // j == i^1
    const float a2 = T[(i ^ 2) * 4 + i] + vx2;
    const float a3 = T[(i ^ 3) * 4 + i] + vx3;
    const float a4 = T[16 + i];                    // j == 4, v[4] = 0
    float m = fmaxf(fmaxf(a0, a1), fmaxf(fmaxf(a2, a3), a4));
    v = m + __logf(__expf(a0 - m) + __expf(a1 - m) + __expf(a2 - m) +
                   __expf(a3 - m) + __expf(a4 - m));
  }
  // logZ[b] = lse over the 4 lanes of v
  float m1 = fmaxf(v, __shfl_xor(v, 1));
  m1 = fmaxf(m1, __shfl_xor(m1, 2));
  float e = __expf(v - m1);
  e += __shfl_xor(e, 1);
  e += __shfl_xor(e, 2);
  const float lz = m1 + __logf(e);
  if (i == 0) logz[b] = lz * (1.0f / (float)T_NTIME);
}

// ---------- K3: out[t][b][8..15] -= logZ[b]/T ----------
__global__ void k_sub(float* __restrict__ out, const float* __restrict__ logz) {
  const long n = (long)blockIdx.x * blockDim.x + threadIdx.x;  // one float4 each
  if (n >= (long)T_NROWS * 2) return;
  const long tb = n >> 1;
  const int b = (int)(tb & (T_NBATCH - 1));
  const float lz = logz[b];
  float4* p = (float4*)(out + tb * T_SIZE + 8 + (n & 1) * 4);
  float4 v = *p;
  v.x -= lz; v.y -= lz; v.z -= lz; v.w -= lz;
  *p = v;
}

extern "C" void kernel_launch(void* const* d_in, const int* in_sizes, int n_in,
                              void* d_out, int out_size, void* d_ws, size_t ws_size,
                              hipStream_t stream) {
  const float* x    = (const float*)d_in[0];
  const float* W    = (const float*)d_in[1];
  const float* bias = (const float*)d_in[2];
  float* out = (float*)d_out;
  float* ws  = (float*)d_ws;

  // pick chunk count that fits workspace: mats = C*128*20 f32, logz = 128 f32
  int C = 64;
  while (C > 1 && (size_t)((long)C * T_NBATCH * 20 + T_NBATCH) * 4 > ws_size) C >>= 1;
  float* mats = ws;
  float* logz = ws + (long)C * T_NBATCH * 20;

  k_gemm_act<<<T_NROWS / 512, 256, 0, stream>>>(x, W, bias, out);

  const int thr2 = C * T_NBATCH * 8;
  k_scan_chunks<<<thr2 / 256, 256, 0, stream>>>(out, mats, C);
  k_combine<<<1, 512, 0, stream>>>(mats, logz, C);
  k_sub<<<(T_NROWS * 2) / 256, 256, 0, stream>>>(out, logz);
}